// Round 5
// baseline (451.156 us; speedup 1.0000x reference)
//
#include <hip/hip_runtime.h>
#include <hip/hip_bf16.h>
#include <hip/hip_fp16.h>

#define N_NODES 100000
#define N_EDGES 1600000
#define IN_DIM 256
#define HIDDEN 128
#define NCLS 40

#define N_BUCKETS 256
#define NPB 391          // nodes per bucket = ceil(100000/256)
#define BCAP 8192        // bucket capacity (mean 6256, +24 sigma)
#define EPT 16           // edges per thread in k_bin
#define BIN_WG 4096      // edges per workgroup in k_bin (256*16)

typedef __attribute__((ext_vector_type(8))) _Float16 half8;
typedef __attribute__((ext_vector_type(4))) float floatx4;

// ---------------- CSR build (bucketed) ----------------

// Phase 1: partition edges into 256 dst-range buckets with coalesced-ish writes.
__global__ __launch_bounds__(256) void k_bin(const int* __restrict__ src, const int* __restrict__ dst,
                                             int* __restrict__ bfill,
                                             int* __restrict__ bsrc, int* __restrict__ bdst) {
    __shared__ int hist[N_BUCKETS];
    __shared__ int base[N_BUCKETS];
    const int t = threadIdx.x;
    hist[t] = 0;
    __syncthreads();
    const long e0 = (long)blockIdx.x * BIN_WG;
    int msrc[EPT], mdst[EPT], moff[EPT];
    #pragma unroll
    for (int i = 0; i < EPT; i++) {
        long e = e0 + t + i * 256;
        if (e < N_EDGES) {
            msrc[i] = src[e];
            mdst[i] = dst[e];
            moff[i] = atomicAdd(&hist[mdst[i] / NPB], 1);
        } else {
            mdst[i] = -1;
        }
    }
    __syncthreads();
    int h = hist[t];
    base[t] = (h > 0) ? atomicAdd(&bfill[t], h) : 0;
    __syncthreads();
    #pragma unroll
    for (int i = 0; i < EPT; i++) {
        if (mdst[i] >= 0) {
            int b = mdst[i] / NPB;
            int p = base[b] + moff[i];
            bsrc[b * BCAP + p] = msrc[i];
            bdst[b * BCAP + p] = mdst[i];
        }
    }
}

// Phase 2a: per-bucket degree histogram + global bucket prefix + in-bucket scan.
// Produces row_ptr AND dinv; replaces k_count/scanA/scanB/scanC/k_dinv.
__global__ __launch_bounds__(256) void k_hist2(const int* __restrict__ bfill, const int* __restrict__ bdst,
                                               int* __restrict__ row_ptr, float* __restrict__ dinv) {
    __shared__ int h[NPB];
    __shared__ int sred[4];
    const int b  = blockIdx.x;
    const int nb = b * NPB;
    const int nn = min(NPB, N_NODES - nb);
    const int t  = threadIdx.x;
    // base_b = sum_{j<b} bfill[j]
    int v = (t < b) ? bfill[t] : 0;
    #pragma unroll
    for (int d = 32; d > 0; d >>= 1) v += __shfl_down(v, d, 64);
    if ((t & 63) == 0) sred[t >> 6] = v;
    for (int i = t; i < NPB; i += 256) h[i] = 0;
    __syncthreads();
    const int base_b = sred[0] + sred[1] + sred[2] + sred[3];
    const int n = bfill[b];
    for (int i = t; i < n; i += 256) atomicAdd(&h[bdst[b * BCAP + i] - nb], 1);
    __syncthreads();
    if (t < 64) {   // wave 0: exclusive scan of h[0..nn-1]
        int carry = 0;
        #pragma unroll
        for (int c = 0; c < (NPB + 63) / 64; c++) {
            int idx = c * 64 + t;
            int hv = (idx < nn) ? h[idx] : 0;
            int s = hv;
            #pragma unroll
            for (int d2 = 1; d2 < 64; d2 <<= 1) {
                int u = __shfl_up(s, d2, 64);
                if (t >= d2) s += u;
            }
            if (idx < nn) {
                row_ptr[nb + idx] = base_b + carry + (s - hv);
                dinv[nb + idx] = rsqrtf((float)(hv + 1));   // +1 self-loop
            }
            carry += __shfl(s, 63, 64);
        }
    }
    if (b == 0 && t == 0) row_ptr[N_NODES] = N_EDGES;
}

// Phase 2b: per-bucket scatter, LDS fill counters; col writes stay in a ~25 KB window.
__global__ __launch_bounds__(256) void k_scatter2(const int* __restrict__ bfill,
                                                  const int* __restrict__ bsrc, const int* __restrict__ bdst,
                                                  const int* __restrict__ row_ptr, int* __restrict__ col) {
    __shared__ int f[NPB];
    const int b = blockIdx.x;
    const int nb = b * NPB;
    const int nn = min(NPB, N_NODES - nb);
    for (int i = threadIdx.x; i < nn; i += 256) f[i] = 0;
    __syncthreads();
    const int n = bfill[b];
    for (int i = threadIdx.x; i < n; i += 256) {
        int d = bdst[b * BCAP + i];
        int s = bsrc[b * BCAP + i];
        int pos = row_ptr[d] + atomicAdd(&f[d - nb], 1);
        col[pos] = s;
    }
}

// ---------------- W1 -> transposed fp16 (once, tiny) ----------------

__global__ __launch_bounds__(256) void k_w1t(const float* __restrict__ W1, __half* __restrict__ W1T) {
    int i = blockIdx.x * 256 + threadIdx.x;
    if (i < IN_DIM * HIDDEN) {
        int k = i >> 7;
        int n = i & 127;
        W1T[n * IN_DIM + k] = __float2half_rn(W1[i]);
    }
}

// ---------------- GEMM1 (MFMA f16): H1s = dinv ⊙ (X @ W1) -> fp16 ----------------

__global__ __launch_bounds__(256) void k_gemm1(const float* __restrict__ X,
                                               const __half* __restrict__ W1T,
                                               const float* __restrict__ dinv,
                                               __half* __restrict__ H1s) {
    __shared__ __align__(16) _Float16 Asm[64][72];
    __shared__ __align__(16) _Float16 Bsm[128][72];
    const int tid  = threadIdx.x;
    const int wave = tid >> 6;
    const int lane = tid & 63;
    const int m16  = lane & 15;
    const int kq   = lane >> 4;
    const int row0 = blockIdx.x * 64;

    floatx4 acc[8];
    #pragma unroll
    for (int i = 0; i < 8; i++) acc[i] = (floatx4)0.f;

    for (int kc = 0; kc < 4; kc++) {
        #pragma unroll
        for (int it = 0; it < 2; it++) {
            int u = tid + it * 256;
            int r = u >> 3, j = u & 7;
            int gr = row0 + r;
            float4 x0 = make_float4(0.f, 0.f, 0.f, 0.f), x1 = x0;
            if (gr < N_NODES) {
                const float* p = &X[(long)gr * IN_DIM + kc * 64 + j * 8];
                x0 = *(const float4*)p;
                x1 = *(const float4*)(p + 4);
            }
            half8 h;
            h[0] = (_Float16)x0.x; h[1] = (_Float16)x0.y; h[2] = (_Float16)x0.z; h[3] = (_Float16)x0.w;
            h[4] = (_Float16)x1.x; h[5] = (_Float16)x1.y; h[6] = (_Float16)x1.z; h[7] = (_Float16)x1.w;
            *(half8*)&Asm[r][j * 8] = h;
        }
        #pragma unroll
        for (int it = 0; it < 4; it++) {
            int u = tid + it * 256;
            int n = u >> 3, j = u & 7;
            float4 w = *(const float4*)&W1T[n * IN_DIM + kc * 64 + j * 8];
            *(float4*)&Bsm[n][j * 8] = w;
        }
        __syncthreads();
        #pragma unroll
        for (int ks = 0; ks < 2; ks++) {
            half8 a = *(const half8*)&Asm[wave * 16 + m16][ks * 32 + kq * 8];
            #pragma unroll
            for (int nt = 0; nt < 8; nt++) {
                half8 b = *(const half8*)&Bsm[nt * 16 + m16][ks * 32 + kq * 8];
                acc[nt] = __builtin_amdgcn_mfma_f32_16x16x32_f16(a, b, acc[nt], 0, 0, 0);
            }
        }
        __syncthreads();
    }
    const int gr0 = row0 + wave * 16 + kq * 4;
    float dd[4];
    #pragma unroll
    for (int r = 0; r < 4; r++) dd[r] = (gr0 + r < N_NODES) ? dinv[gr0 + r] : 0.f;
    #pragma unroll
    for (int nt = 0; nt < 8; nt++) {
        int c = nt * 16 + m16;
        #pragma unroll
        for (int r = 0; r < 4; r++) {
            if (gr0 + r < N_NODES)
                H1s[(long)(gr0 + r) * HIDDEN + c] = __float2half_rn(dd[r] * acc[nt][r]);
        }
    }
}

// ---------------- Fused Agg1 + bias + ReLU + GEMM2 + dinv-pre-scale -> H2s fp16 ----------------
// One wave per node: gather-sum 128 feats (2/lane), row to LDS fp32, dot with LDS W2.

__global__ __launch_bounds__(256) void k_agg1f(const __half* __restrict__ H1s,
                                               const int* __restrict__ row_ptr,
                                               const int* __restrict__ col,
                                               const float* __restrict__ dinv,
                                               const float* __restrict__ b1,
                                               const float* __restrict__ W2,
                                               __half* __restrict__ H2s) {
    __shared__ float Ws[HIDDEN * NCLS];     // 20 KB, [k][c]
    __shared__ float rowbuf[4][HIDDEN];     // 2 KB
    for (int i = threadIdx.x; i < HIDDEN * NCLS; i += 256) Ws[i] = W2[i];
    __syncthreads();

    const int wave = threadIdx.x >> 6;
    const int lane = threadIdx.x & 63;
    const int d = blockIdx.x * 4 + wave;    // N_NODES % 4 == 0
    int e0 = row_ptr[d], e1 = row_ptr[d + 1];
    const __half2* base = (const __half2*)H1s;   // row stride 64 half2
    float ax = 0.f, ay = 0.f;
    int e = e0;
    for (; e + 3 < e1; e += 4) {
        int s0 = col[e], s1 = col[e + 1], s2 = col[e + 2], s3 = col[e + 3];
        float2 f0 = __half22float2(base[(long)s0 * 64 + lane]);
        float2 f1 = __half22float2(base[(long)s1 * 64 + lane]);
        float2 f2 = __half22float2(base[(long)s2 * 64 + lane]);
        float2 f3 = __half22float2(base[(long)s3 * 64 + lane]);
        ax += f0.x + f1.x + f2.x + f3.x;
        ay += f0.y + f1.y + f2.y + f3.y;
    }
    for (; e < e1; e++) {
        float2 f = __half22float2(base[(long)col[e] * 64 + lane]);
        ax += f.x; ay += f.y;
    }
    float2 fs = __half22float2(base[(long)d * 64 + lane]);   // self-loop (pre-scaled)
    ax += fs.x; ay += fs.y;
    const float dd = dinv[d];
    float2 bb = ((const float2*)b1)[lane];
    rowbuf[wave][lane * 2]     = fmaxf(dd * ax + bb.x, 0.f);
    rowbuf[wave][lane * 2 + 1] = fmaxf(dd * ay + bb.y, 0.f);
    __syncthreads();   // uniform: every thread reaches exactly once

    if (lane < NCLS) {
        float acc = 0.f;
        #pragma unroll 4
        for (int k = 0; k < HIDDEN; k += 4) {
            float4 r = *(const float4*)&rowbuf[wave][k];
            acc += r.x * Ws[(k + 0) * NCLS + lane];
            acc += r.y * Ws[(k + 1) * NCLS + lane];
            acc += r.z * Ws[(k + 2) * NCLS + lane];
            acc += r.w * Ws[(k + 3) * NCLS + lane];
        }
        H2s[(long)d * NCLS + lane] = __float2half_rn(dd * acc);
    }
}

// ---------------- Aggregation 2 (+bias) -> fp32 out. 3 nodes x 20 half2-lanes per wave ----------------

__global__ __launch_bounds__(256) void k_agg2(const __half* __restrict__ H2s,
                                              const int* __restrict__ row_ptr,
                                              const int* __restrict__ col,
                                              const float* __restrict__ dinv,
                                              const float* __restrict__ b2,
                                              float* __restrict__ out) {
    const int wave = threadIdx.x >> 6;
    const int lane = threadIdx.x & 63;
    const int g = lane / 20;              // 0..2 active, 3 idle
    const int f = lane - g * 20;          // 0..19 -> feats 2f,2f+1
    const int d = blockIdx.x * 12 + wave * 3 + g;
    const bool act = (g < 3) && (d < N_NODES);
    int e0 = 0, e1 = 0;
    if (act) { e0 = row_ptr[d]; e1 = row_ptr[d + 1]; }
    const __half2* base2 = (const __half2*)H2s;   // row stride 20 half2
    float sx = 0.f, sy = 0.f;
    int e = e0;
    while (__any(e < e1)) {
        if (e < e1) {
            float2 v = __half22float2(base2[(long)col[e] * 20 + f]);
            sx += v.x; sy += v.y;
        }
        if (e + 1 < e1) {
            float2 v = __half22float2(base2[(long)col[e + 1] * 20 + f]);
            sx += v.x; sy += v.y;
        }
        e += 2;
    }
    if (act) {
        float2 v = __half22float2(base2[(long)d * 20 + f]);   // self-loop (pre-scaled)
        sx += v.x; sy += v.y;
        float dd = dinv[d];
        float2 bb = ((const float2*)b2)[f];
        ((float2*)out)[(long)d * 20 + f] = make_float2(dd * sx + bb.x, dd * sy + bb.y);
    }
}

// ---------------- launch ----------------

extern "C" void kernel_launch(void* const* d_in, const int* in_sizes, int n_in,
                              void* d_out, int out_size, void* d_ws, size_t ws_size,
                              hipStream_t stream) {
    const float* x  = (const float*)d_in[0];
    const int*   ei = (const int*)d_in[1];
    const float* W1 = (const float*)d_in[2];
    const float* b1 = (const float*)d_in[3];
    const float* W2 = (const float*)d_in[4];
    const float* b2 = (const float*)d_in[5];
    const int* srcE = ei;
    const int* dstE = ei + N_EDGES;

    int*   row_ptr = (int*)d_ws;                 // 100032
    int*   bfill   = row_ptr + 100032;           // 256
    int*   col     = bfill + 256;                // 1600000
    float* dinv    = (float*)(col + N_EDGES);    // 100032
    __half* H1s    = (__half*)(dinv + 100032);   // 12.8M halfs (25.6 MB)
    __half* H2s    = H1s + (long)N_NODES * HIDDEN;  // 4M halfs (8 MB)
    __half* W1T    = H2s + (long)N_NODES * NCLS;    // 32768 halfs
    // bucket arrays alias H1s (dead before k_gemm1 writes H1s)
    int*   bsrc    = (int*)H1s;                  // 2.1M ints (8 MB)
    int*   bdst    = bsrc + N_BUCKETS * BCAP;    // 2.1M ints (8 MB)

    hipMemsetAsync(bfill, 0, N_BUCKETS * sizeof(int), stream);

    k_bin     <<<(N_EDGES + BIN_WG - 1) / BIN_WG, 256, 0, stream>>>(srcE, dstE, bfill, bsrc, bdst);
    k_hist2   <<<N_BUCKETS, 256, 0, stream>>>(bfill, bdst, row_ptr, dinv);
    k_scatter2<<<N_BUCKETS, 256, 0, stream>>>(bfill, bsrc, bdst, row_ptr, col);
    k_w1t     <<<(IN_DIM * HIDDEN + 255) / 256, 256, 0, stream>>>(W1, W1T);

    k_gemm1   <<<(N_NODES + 63) / 64, 256, 0, stream>>>(x, W1T, dinv, H1s);
    k_agg1f   <<<N_NODES / 4, 256, 0, stream>>>(H1s, row_ptr, col, dinv, b1, W2, H2s);
    k_agg2    <<<(N_NODES + 11) / 12, 256, 0, stream>>>(H2s, row_ptr, col, dinv, b2, (float*)d_out);
}

// Round 6
// 429.884 us; speedup vs baseline: 1.0495x; 1.0495x over previous
//
#include <hip/hip_runtime.h>
#include <hip/hip_bf16.h>
#include <hip/hip_fp16.h>

#define N_NODES 100000
#define N_EDGES 1600000
#define IN_DIM 256
#define HIDDEN 128
#define NCLS 40

#define N_BUCKETS 256
#define NPB 391          // nodes per bucket = ceil(100000/256)
#define BCAP 8192        // bucket capacity (mean 6256, +24 sigma)
#define EPT 16           // edges per thread in k_bin
#define BIN_WG 4096      // edges per workgroup in k_bin (256*16)

typedef __attribute__((ext_vector_type(8))) _Float16 half8;
typedef __attribute__((ext_vector_type(4))) float floatx4;

// ---------------- CSR build (bucketed) ----------------

// Phase 1: partition edges into 256 dst-range buckets.
__global__ __launch_bounds__(256) void k_bin(const int* __restrict__ src, const int* __restrict__ dst,
                                             int* __restrict__ bfill,
                                             int* __restrict__ bsrc, int* __restrict__ bdst) {
    __shared__ int hist[N_BUCKETS];
    __shared__ int base[N_BUCKETS];
    const int t = threadIdx.x;
    hist[t] = 0;
    __syncthreads();
    const long e0 = (long)blockIdx.x * BIN_WG;
    int msrc[EPT], mdst[EPT], moff[EPT];
    #pragma unroll
    for (int i = 0; i < EPT; i++) {
        long e = e0 + t + i * 256;
        if (e < N_EDGES) {
            msrc[i] = src[e];
            mdst[i] = dst[e];
            moff[i] = atomicAdd(&hist[mdst[i] / NPB], 1);
        } else {
            mdst[i] = -1;
        }
    }
    __syncthreads();
    int h = hist[t];
    base[t] = (h > 0) ? atomicAdd(&bfill[t], h) : 0;
    __syncthreads();
    #pragma unroll
    for (int i = 0; i < EPT; i++) {
        if (mdst[i] >= 0) {
            int b = mdst[i] / NPB;
            int p = base[b] + moff[i];
            bsrc[b * BCAP + p] = msrc[i];
            bdst[b * BCAP + p] = mdst[i];
        }
    }
}

// Phase 2 (merged): per-bucket histogram -> bucket-prefix -> in-bucket scan ->
// row_ptr + dinv + scatter to col, all in one kernel (prefix stays in LDS).
__global__ __launch_bounds__(256) void k_build(const int* __restrict__ bfill,
                                               const int* __restrict__ bsrc, const int* __restrict__ bdst,
                                               int* __restrict__ row_ptr, float* __restrict__ dinv,
                                               int* __restrict__ col) {
    __shared__ int h[NPB];
    __shared__ int pfx[NPB];
    __shared__ int sred[4];
    const int b  = blockIdx.x;
    const int nb = b * NPB;
    const int nn = min(NPB, N_NODES - nb);
    const int t  = threadIdx.x;
    // base_b = sum_{j<b} bfill[j]
    int v = (t < b) ? bfill[t] : 0;
    #pragma unroll
    for (int dl = 32; dl > 0; dl >>= 1) v += __shfl_down(v, dl, 64);
    if ((t & 63) == 0) sred[t >> 6] = v;
    for (int i = t; i < NPB; i += 256) h[i] = 0;
    __syncthreads();
    const int base_b = sred[0] + sred[1] + sred[2] + sred[3];
    const int n = bfill[b];
    for (int i = t; i < n; i += 256) atomicAdd(&h[bdst[b * BCAP + i] - nb], 1);
    __syncthreads();
    if (t < 64) {   // wave 0: exclusive scan of degrees
        int carry = 0;
        #pragma unroll
        for (int c = 0; c < (NPB + 63) / 64; c++) {
            int idx = c * 64 + t;
            int hv = (idx < nn) ? h[idx] : 0;
            int s = hv;
            #pragma unroll
            for (int d2 = 1; d2 < 64; d2 <<= 1) {
                int u = __shfl_up(s, d2, 64);
                if (t >= d2) s += u;
            }
            if (idx < nn) {
                int ex = base_b + carry + (s - hv);
                pfx[idx] = ex;
                row_ptr[nb + idx] = ex;
                dinv[nb + idx] = rsqrtf((float)(hv + 1));   // +1 self-loop
            }
            carry += __shfl(s, 63, 64);
        }
    }
    __syncthreads();
    for (int i = t; i < nn; i += 256) h[i] = 0;   // reuse as fill counters
    __syncthreads();
    for (int i = t; i < n; i += 256) {
        int dd = bdst[b * BCAP + i];
        int ss = bsrc[b * BCAP + i];
        int pos = pfx[dd - nb] + atomicAdd(&h[dd - nb], 1);
        col[pos] = ss;
    }
    if (b == 0 && t == 0) row_ptr[N_NODES] = N_EDGES;
}

// ---------------- W1 -> transposed fp16 (once, tiny) ----------------

__global__ __launch_bounds__(256) void k_w1t(const float* __restrict__ W1, __half* __restrict__ W1T) {
    int i = blockIdx.x * 256 + threadIdx.x;
    if (i < IN_DIM * HIDDEN) {
        int k = i >> 7;
        int n = i & 127;
        W1T[n * IN_DIM + k] = __float2half_rn(W1[i]);
    }
}

// ---------------- GEMM1 (MFMA f16): H1s = dinv ⊙ (X @ W1) -> fp16 ----------------

__global__ __launch_bounds__(256) void k_gemm1(const float* __restrict__ X,
                                               const __half* __restrict__ W1T,
                                               const float* __restrict__ dinv,
                                               __half* __restrict__ H1s) {
    __shared__ __align__(16) _Float16 Asm[64][72];
    __shared__ __align__(16) _Float16 Bsm[128][72];
    const int tid  = threadIdx.x;
    const int wave = tid >> 6;
    const int lane = tid & 63;
    const int m16  = lane & 15;
    const int kq   = lane >> 4;
    const int row0 = blockIdx.x * 64;

    floatx4 acc[8];
    #pragma unroll
    for (int i = 0; i < 8; i++) acc[i] = (floatx4)0.f;

    for (int kc = 0; kc < 4; kc++) {
        #pragma unroll
        for (int it = 0; it < 2; it++) {
            int u = tid + it * 256;
            int r = u >> 3, j = u & 7;
            int gr = row0 + r;
            float4 x0 = make_float4(0.f, 0.f, 0.f, 0.f), x1 = x0;
            if (gr < N_NODES) {
                const float* p = &X[(long)gr * IN_DIM + kc * 64 + j * 8];
                x0 = *(const float4*)p;
                x1 = *(const float4*)(p + 4);
            }
            half8 h;
            h[0] = (_Float16)x0.x; h[1] = (_Float16)x0.y; h[2] = (_Float16)x0.z; h[3] = (_Float16)x0.w;
            h[4] = (_Float16)x1.x; h[5] = (_Float16)x1.y; h[6] = (_Float16)x1.z; h[7] = (_Float16)x1.w;
            *(half8*)&Asm[r][j * 8] = h;
        }
        #pragma unroll
        for (int it = 0; it < 4; it++) {
            int u = tid + it * 256;
            int n = u >> 3, j = u & 7;
            float4 w = *(const float4*)&W1T[n * IN_DIM + kc * 64 + j * 8];
            *(float4*)&Bsm[n][j * 8] = w;
        }
        __syncthreads();
        #pragma unroll
        for (int ks = 0; ks < 2; ks++) {
            half8 a = *(const half8*)&Asm[wave * 16 + m16][ks * 32 + kq * 8];
            #pragma unroll
            for (int nt = 0; nt < 8; nt++) {
                half8 b = *(const half8*)&Bsm[nt * 16 + m16][ks * 32 + kq * 8];
                acc[nt] = __builtin_amdgcn_mfma_f32_16x16x32_f16(a, b, acc[nt], 0, 0, 0);
            }
        }
        __syncthreads();
    }
    const int gr0 = row0 + wave * 16 + kq * 4;
    float dd[4];
    #pragma unroll
    for (int r = 0; r < 4; r++) dd[r] = (gr0 + r < N_NODES) ? dinv[gr0 + r] : 0.f;
    #pragma unroll
    for (int nt = 0; nt < 8; nt++) {
        int c = nt * 16 + m16;
        #pragma unroll
        for (int r = 0; r < 4; r++) {
            if (gr0 + r < N_NODES)
                H1s[(long)(gr0 + r) * HIDDEN + c] = __float2half_rn(dd[r] * acc[nt][r]);
        }
    }
}

// ---------------- Aggregation 1 (+bias+ReLU) -> fp16 H1a. One wave/node, 8-edge unroll ----------------

__global__ __launch_bounds__(256) void k_agg1(const __half* __restrict__ H1s,
                                              const int* __restrict__ row_ptr,
                                              const int* __restrict__ col,
                                              const float* __restrict__ dinv,
                                              const float* __restrict__ b1,
                                              __half* __restrict__ H1a) {
    int d = blockIdx.x * 4 + (threadIdx.x >> 6);
    int lane = threadIdx.x & 63;
    int e0 = row_ptr[d], e1 = row_ptr[d + 1];
    const __half2* base = (const __half2*)H1s;   // row stride 64 half2
    float ax = 0.f, ay = 0.f;
    int e = e0;
    for (; e + 7 < e1; e += 8) {
        int s0 = col[e],     s1 = col[e + 1], s2 = col[e + 2], s3 = col[e + 3];
        int s4 = col[e + 4], s5 = col[e + 5], s6 = col[e + 6], s7 = col[e + 7];
        float2 f0 = __half22float2(base[(long)s0 * 64 + lane]);
        float2 f1 = __half22float2(base[(long)s1 * 64 + lane]);
        float2 f2 = __half22float2(base[(long)s2 * 64 + lane]);
        float2 f3 = __half22float2(base[(long)s3 * 64 + lane]);
        float2 f4 = __half22float2(base[(long)s4 * 64 + lane]);
        float2 f5 = __half22float2(base[(long)s5 * 64 + lane]);
        float2 f6 = __half22float2(base[(long)s6 * 64 + lane]);
        float2 f7 = __half22float2(base[(long)s7 * 64 + lane]);
        ax += (f0.x + f1.x) + (f2.x + f3.x) + ((f4.x + f5.x) + (f6.x + f7.x));
        ay += (f0.y + f1.y) + (f2.y + f3.y) + ((f4.y + f5.y) + (f6.y + f7.y));
    }
    for (; e < e1; e++) {
        float2 f = __half22float2(base[(long)col[e] * 64 + lane]);
        ax += f.x; ay += f.y;
    }
    float2 fs = __half22float2(base[(long)d * 64 + lane]);   // self-loop (pre-scaled)
    ax += fs.x; ay += fs.y;
    float dd = dinv[d];
    float2 bb = ((const float2*)b1)[lane];
    float ox = fmaxf(dd * ax + bb.x, 0.f);
    float oy = fmaxf(dd * ay + bb.y, 0.f);
    ((__half2*)H1a)[(long)d * 64 + lane] = __halves2half2(__float2half_rn(ox), __float2half_rn(oy));
}

// ---------------- GEMM2: H2s = dinv ⊙ (H1a @ W2) -> fp16, W2 in LDS, x4 grid-stride ----------------

__global__ __launch_bounds__(256) void k_gemm2(const __half* __restrict__ H1a,
                                               const float* __restrict__ W2,
                                               const float* __restrict__ dinv,
                                               __half* __restrict__ H2s) {
    __shared__ float Ws[HIDDEN * NCLS];   // 20 KB
    for (int i = threadIdx.x; i < HIDDEN * NCLS; i += 256) Ws[i] = W2[i];
    __syncthreads();
    #pragma unroll
    for (int it = 0; it < 4; it++) {
        long gid = (long)blockIdx.x * 1024 + it * 256 + threadIdx.x;
        if (gid >= (long)N_NODES * NCLS) continue;
        int row = (int)(gid / NCLS);
        int c   = (int)(gid - (long)row * NCLS);
        const float4* hrow4 = (const float4*)&H1a[(long)row * HIDDEN];
        float acc = 0.f;
        #pragma unroll
        for (int k8 = 0; k8 < HIDDEN / 8; k8++) {
            union { float4 v; __half2 h[4]; } u;
            u.v = hrow4[k8];
            float2 f0 = __half22float2(u.h[0]), f1 = __half22float2(u.h[1]);
            float2 f2 = __half22float2(u.h[2]), f3 = __half22float2(u.h[3]);
            int kb = k8 * 8;
            acc += f0.x * Ws[(kb + 0) * NCLS + c];
            acc += f0.y * Ws[(kb + 1) * NCLS + c];
            acc += f1.x * Ws[(kb + 2) * NCLS + c];
            acc += f1.y * Ws[(kb + 3) * NCLS + c];
            acc += f2.x * Ws[(kb + 4) * NCLS + c];
            acc += f2.y * Ws[(kb + 5) * NCLS + c];
            acc += f3.x * Ws[(kb + 6) * NCLS + c];
            acc += f3.y * Ws[(kb + 7) * NCLS + c];
        }
        H2s[gid] = __float2half_rn(dinv[row] * acc);
    }
}

// ---------------- Aggregation 2 (+bias) -> fp32 out. 3 nodes x 20 half2-lanes per wave ----------------

__global__ __launch_bounds__(256) void k_agg2(const __half* __restrict__ H2s,
                                              const int* __restrict__ row_ptr,
                                              const int* __restrict__ col,
                                              const float* __restrict__ dinv,
                                              const float* __restrict__ b2,
                                              float* __restrict__ out) {
    const int wave = threadIdx.x >> 6;
    const int lane = threadIdx.x & 63;
    const int g = lane / 20;              // 0..2 active, 3 idle
    const int f = lane - g * 20;          // 0..19 -> feats 2f,2f+1
    const int d = blockIdx.x * 12 + wave * 3 + g;
    const bool act = (g < 3) && (d < N_NODES);
    int e0 = 0, e1 = 0;
    if (act) { e0 = row_ptr[d]; e1 = row_ptr[d + 1]; }
    const __half2* base2 = (const __half2*)H2s;   // row stride 20 half2
    float sx = 0.f, sy = 0.f;
    int e = e0;
    while (__any(e < e1)) {
        if (e < e1) {
            float2 v = __half22float2(base2[(long)col[e] * 20 + f]);
            sx += v.x; sy += v.y;
        }
        if (e + 1 < e1) {
            float2 v = __half22float2(base2[(long)col[e + 1] * 20 + f]);
            sx += v.x; sy += v.y;
        }
        e += 2;
    }
    if (act) {
        float2 v = __half22float2(base2[(long)d * 20 + f]);   // self-loop (pre-scaled)
        sx += v.x; sy += v.y;
        float dd = dinv[d];
        float2 bb = ((const float2*)b2)[f];
        ((float2*)out)[(long)d * 20 + f] = make_float2(dd * sx + bb.x, dd * sy + bb.y);
    }
}

// ---------------- launch ----------------

extern "C" void kernel_launch(void* const* d_in, const int* in_sizes, int n_in,
                              void* d_out, int out_size, void* d_ws, size_t ws_size,
                              hipStream_t stream) {
    const float* x  = (const float*)d_in[0];
    const int*   ei = (const int*)d_in[1];
    const float* W1 = (const float*)d_in[2];
    const float* b1 = (const float*)d_in[3];
    const float* W2 = (const float*)d_in[4];
    const float* b2 = (const float*)d_in[5];
    const int* srcE = ei;
    const int* dstE = ei + N_EDGES;

    int*   row_ptr = (int*)d_ws;                 // 100032
    int*   bfill   = row_ptr + 100032;           // 256
    int*   col     = bfill + 256;                // 1600000
    float* dinv    = (float*)(col + N_EDGES);    // 100032
    __half* H1s    = (__half*)(dinv + 100032);   // 12.8M halfs (25.6 MB)
    __half* H1a    = H1s + (long)N_NODES * HIDDEN;  // 12.8M halfs
    __half* H2s    = H1a + (long)N_NODES * HIDDEN;  // 4M halfs (8 MB)
    __half* W1T    = H2s + (long)N_NODES * NCLS;    // 32768 halfs
    // bucket arrays alias H1s/H1a (dead before k_gemm1 writes H1s)
    int*   bsrc    = (int*)H1s;                  // 2.1M ints (8 MB)
    int*   bdst    = bsrc + N_BUCKETS * BCAP;    // 2.1M ints (8 MB)

    hipMemsetAsync(bfill, 0, N_BUCKETS * sizeof(int), stream);

    k_bin   <<<(N_EDGES + BIN_WG - 1) / BIN_WG, 256, 0, stream>>>(srcE, dstE, bfill, bsrc, bdst);
    k_build <<<N_BUCKETS, 256, 0, stream>>>(bfill, bsrc, bdst, row_ptr, dinv, col);
    k_w1t   <<<(IN_DIM * HIDDEN + 255) / 256, 256, 0, stream>>>(W1, W1T);

    k_gemm1 <<<(N_NODES + 63) / 64, 256, 0, stream>>>(x, W1T, dinv, H1s);
    k_agg1  <<<N_NODES / 4, 256, 0, stream>>>(H1s, row_ptr, col, dinv, b1, H1a);
    k_gemm2 <<<(int)(((long)N_NODES * NCLS + 1023) / 1024), 256, 0, stream>>>(H1a, W2, dinv, H2s);
    k_agg2  <<<(N_NODES + 11) / 12, 256, 0, stream>>>(H2s, row_ptr, col, dinv, b2, (float*)d_out);
}

// Round 7
// 404.332 us; speedup vs baseline: 1.1158x; 1.0632x over previous
//
#include <hip/hip_runtime.h>
#include <hip/hip_bf16.h>
#include <hip/hip_fp16.h>

#define N_NODES 100000
#define N_EDGES 1600000
#define IN_DIM 256
#define HIDDEN 128
#define NCLS 40
#define NCLS_PAD 48      // padded to 3 MFMA n-tiles

#define N_BUCKETS 256
#define NPB 391          // nodes per bucket = ceil(100000/256)
#define BCAP 8192        // bucket capacity (mean 6256, +24 sigma)
#define EPT 16           // edges per thread in k_bin
#define BIN_WG 4096      // edges per workgroup in k_bin (256*16)
#define BIN_BLOCKS 391   // ceil(N_EDGES / BIN_WG)

typedef __attribute__((ext_vector_type(8))) _Float16 half8;
typedef __attribute__((ext_vector_type(4))) float floatx4;

// ---------------- k_bin: edge bucketing + (fused) weight prep ----------------

__global__ __launch_bounds__(256) void k_bin(const int* __restrict__ src, const int* __restrict__ dst,
                                             int* __restrict__ bfill,
                                             int* __restrict__ bsrc, int* __restrict__ bdst,
                                             const float* __restrict__ W1, __half* __restrict__ W1T,
                                             const float* __restrict__ W2, __half* __restrict__ W2T) {
    const int t = threadIdx.x;
    if (blockIdx.x >= BIN_BLOCKS) {
        int wb = blockIdx.x - BIN_BLOCKS;
        if (wb < 128) {          // W1T: [n][k] fp16, n<128, k<256
            int i = wb * 256 + t;            // over 32768
            int k = i >> 7, n = i & 127;
            W1T[n * IN_DIM + k] = __float2half_rn(W1[i]);
        } else {                 // W2T: [n][k] fp16, 48 x 128, zero-pad n>=40
            for (int i = t; i < NCLS_PAD * HIDDEN; i += 256) {
                int n = i >> 7, k = i & 127;
                W2T[n * HIDDEN + k] = (n < NCLS) ? __float2half_rn(W2[k * NCLS + n]) : __float2half_rn(0.f);
            }
        }
        return;
    }
    __shared__ int hist[N_BUCKETS];
    __shared__ int base[N_BUCKETS];
    hist[t] = 0;
    __syncthreads();
    const long e0 = (long)blockIdx.x * BIN_WG;
    int msrc[EPT], mdst[EPT], moff[EPT];
    #pragma unroll
    for (int i = 0; i < EPT; i++) {
        long e = e0 + t + i * 256;
        if (e < N_EDGES) {
            msrc[i] = src[e];
            mdst[i] = dst[e];
            moff[i] = atomicAdd(&hist[mdst[i] / NPB], 1);
        } else {
            mdst[i] = -1;
        }
    }
    __syncthreads();
    int h = hist[t];
    base[t] = (h > 0) ? atomicAdd(&bfill[t], h) : 0;
    __syncthreads();
    #pragma unroll
    for (int i = 0; i < EPT; i++) {
        if (mdst[i] >= 0) {
            int b = mdst[i] / NPB;
            int p = base[b] + moff[i];
            bsrc[b * BCAP + p] = msrc[i];
            bdst[b * BCAP + p] = mdst[i];
        }
    }
}

// ---------------- k_build: histogram -> prefix -> row_ptr/dinv -> scatter ----------------

__global__ __launch_bounds__(256) void k_build(const int* __restrict__ bfill,
                                               const int* __restrict__ bsrc, const int* __restrict__ bdst,
                                               int* __restrict__ row_ptr, float* __restrict__ dinv,
                                               int* __restrict__ col) {
    __shared__ int h[NPB];
    __shared__ int pfx[NPB];
    __shared__ int sred[4];
    const int b  = blockIdx.x;
    const int nb = b * NPB;
    const int nn = min(NPB, N_NODES - nb);
    const int t  = threadIdx.x;
    int v = (t < b) ? bfill[t] : 0;
    #pragma unroll
    for (int dl = 32; dl > 0; dl >>= 1) v += __shfl_down(v, dl, 64);
    if ((t & 63) == 0) sred[t >> 6] = v;
    for (int i = t; i < NPB; i += 256) h[i] = 0;
    __syncthreads();
    const int base_b = sred[0] + sred[1] + sred[2] + sred[3];
    const int n = bfill[b];
    for (int i = t; i < n; i += 256) atomicAdd(&h[bdst[b * BCAP + i] - nb], 1);
    __syncthreads();
    if (t < 64) {   // wave 0: exclusive scan of degrees
        int carry = 0;
        #pragma unroll
        for (int c = 0; c < (NPB + 63) / 64; c++) {
            int idx = c * 64 + t;
            int hv = (idx < nn) ? h[idx] : 0;
            int s = hv;
            #pragma unroll
            for (int d2 = 1; d2 < 64; d2 <<= 1) {
                int u = __shfl_up(s, d2, 64);
                if (t >= d2) s += u;
            }
            if (idx < nn) {
                int ex = base_b + carry + (s - hv);
                pfx[idx] = ex;
                row_ptr[nb + idx] = ex;
                dinv[nb + idx] = rsqrtf((float)(hv + 1));   // +1 self-loop
            }
            carry += __shfl(s, 63, 64);
        }
    }
    __syncthreads();
    for (int i = t; i < nn; i += 256) h[i] = 0;   // reuse as fill counters
    __syncthreads();
    for (int i = t; i < n; i += 256) {
        int dd = bdst[b * BCAP + i];
        int ss = bsrc[b * BCAP + i];
        int pos = pfx[dd - nb] + atomicAdd(&h[dd - nb], 1);
        col[pos] = ss;
    }
    if (b == 0 && t == 0) row_ptr[N_NODES] = N_EDGES;
}

// ---------------- GEMM1 (MFMA f16, 128x128 tile): H1s = dinv ⊙ (X @ W1) -> fp16 ----------------
// 4 waves; wave w covers rows [32w, 32w+32) as two 16-row m-tiles. BK=64, 4 chunks.

__global__ __launch_bounds__(256) void k_gemm1(const float* __restrict__ X,
                                               const __half* __restrict__ W1T,
                                               const float* __restrict__ dinv,
                                               __half* __restrict__ H1s) {
    __shared__ __align__(16) _Float16 Asm[128][72];   // 18.4 KB
    __shared__ __align__(16) _Float16 Bsm[128][72];   // 18.4 KB
    const int tid  = threadIdx.x;
    const int wave = tid >> 6;
    const int lane = tid & 63;
    const int m16  = lane & 15;
    const int kq   = lane >> 4;
    const int row0 = blockIdx.x * 128;

    floatx4 acc[2][8];
    #pragma unroll
    for (int mt = 0; mt < 2; mt++)
        #pragma unroll
        for (int i = 0; i < 8; i++) acc[mt][i] = (floatx4)0.f;

    for (int kc = 0; kc < 4; kc++) {
        // stage A: 128 rows x 64 k (fp32 -> f16): 1024 half8-units, 4 iters
        #pragma unroll
        for (int it = 0; it < 4; it++) {
            int u = tid + it * 256;
            int r = u >> 3, j = u & 7;
            int gr = row0 + r;
            float4 x0 = make_float4(0.f, 0.f, 0.f, 0.f), x1 = x0;
            if (gr < N_NODES) {
                const float* p = &X[(long)gr * IN_DIM + kc * 64 + j * 8];
                x0 = *(const float4*)p;
                x1 = *(const float4*)(p + 4);
            }
            half8 h;
            h[0] = (_Float16)x0.x; h[1] = (_Float16)x0.y; h[2] = (_Float16)x0.z; h[3] = (_Float16)x0.w;
            h[4] = (_Float16)x1.x; h[5] = (_Float16)x1.y; h[6] = (_Float16)x1.z; h[7] = (_Float16)x1.w;
            *(half8*)&Asm[r][j * 8] = h;
        }
        // stage B^T: 128 n x 64 k f16: 1024 half8-units, 4 iters
        #pragma unroll
        for (int it = 0; it < 4; it++) {
            int u = tid + it * 256;
            int n = u >> 3, j = u & 7;
            float4 w = *(const float4*)&W1T[n * IN_DIM + kc * 64 + j * 8];
            *(float4*)&Bsm[n][j * 8] = w;
        }
        __syncthreads();
        #pragma unroll
        for (int ks = 0; ks < 2; ks++) {
            half8 a0 = *(const half8*)&Asm[wave * 32 + m16][ks * 32 + kq * 8];
            half8 a1 = *(const half8*)&Asm[wave * 32 + 16 + m16][ks * 32 + kq * 8];
            #pragma unroll
            for (int nt = 0; nt < 8; nt++) {
                half8 b = *(const half8*)&Bsm[nt * 16 + m16][ks * 32 + kq * 8];
                acc[0][nt] = __builtin_amdgcn_mfma_f32_16x16x32_f16(a0, b, acc[0][nt], 0, 0, 0);
                acc[1][nt] = __builtin_amdgcn_mfma_f32_16x16x32_f16(a1, b, acc[1][nt], 0, 0, 0);
            }
        }
        __syncthreads();
    }
    #pragma unroll
    for (int mt = 0; mt < 2; mt++) {
        const int gr0 = row0 + wave * 32 + mt * 16 + kq * 4;
        float dd[4];
        #pragma unroll
        for (int r = 0; r < 4; r++) dd[r] = (gr0 + r < N_NODES) ? dinv[gr0 + r] : 0.f;
        #pragma unroll
        for (int nt = 0; nt < 8; nt++) {
            int c = nt * 16 + m16;
            #pragma unroll
            for (int r = 0; r < 4; r++) {
                if (gr0 + r < N_NODES)
                    H1s[(long)(gr0 + r) * HIDDEN + c] = __float2half_rn(dd[r] * acc[mt][nt][r]);
            }
        }
    }
}

// ---------------- Aggregation 1 (+bias+ReLU) -> fp16 H1a. One wave/node ----------------

__global__ __launch_bounds__(256) void k_agg1(const __half* __restrict__ H1s,
                                              const int* __restrict__ row_ptr,
                                              const int* __restrict__ col,
                                              const float* __restrict__ dinv,
                                              const float* __restrict__ b1,
                                              __half* __restrict__ H1a) {
    int d = blockIdx.x * 4 + (threadIdx.x >> 6);
    int lane = threadIdx.x & 63;
    int e0 = row_ptr[d], e1 = row_ptr[d + 1];
    const __half2* base = (const __half2*)H1s;   // row stride 64 half2
    float ax = 0.f, ay = 0.f;
    int e = e0;
    for (; e + 3 < e1; e += 4) {
        int s0 = col[e], s1 = col[e + 1], s2 = col[e + 2], s3 = col[e + 3];
        float2 f0 = __half22float2(base[(long)s0 * 64 + lane]);
        float2 f1 = __half22float2(base[(long)s1 * 64 + lane]);
        float2 f2 = __half22float2(base[(long)s2 * 64 + lane]);
        float2 f3 = __half22float2(base[(long)s3 * 64 + lane]);
        ax += f0.x + f1.x + f2.x + f3.x;
        ay += f0.y + f1.y + f2.y + f3.y;
    }
    for (; e < e1; e++) {
        float2 f = __half22float2(base[(long)col[e] * 64 + lane]);
        ax += f.x; ay += f.y;
    }
    float2 fs = __half22float2(base[(long)d * 64 + lane]);   // self-loop (pre-scaled)
    ax += fs.x; ay += fs.y;
    float dd = dinv[d];
    float2 bb = ((const float2*)b1)[lane];
    float ox = fmaxf(dd * ax + bb.x, 0.f);
    float oy = fmaxf(dd * ay + bb.y, 0.f);
    ((__half2*)H1a)[(long)d * 64 + lane] = __halves2half2(__float2half_rn(ox), __float2half_rn(oy));
}

// ---------------- GEMM2 (MFMA f16, no LDS): H2s = dinv ⊙ (H1a @ W2) -> fp16 ----------------
// 64 rows/block, wave w -> rows [16w,16w+16). A-frags from H1a, B-frags from W2T (L2-hot).

__global__ __launch_bounds__(256) void k_gemm2(const __half* __restrict__ H1a,
                                               const __half* __restrict__ W2T,
                                               const float* __restrict__ dinv,
                                               __half* __restrict__ H2s) {
    const int wave = threadIdx.x >> 6;
    const int lane = threadIdx.x & 63;
    const int m16  = lane & 15;
    const int kq   = lane >> 4;
    const int rowa = min(blockIdx.x * 64 + wave * 16 + m16, N_NODES - 1);

    floatx4 acc[3];
    #pragma unroll
    for (int i = 0; i < 3; i++) acc[i] = (floatx4)0.f;

    #pragma unroll
    for (int ks = 0; ks < 4; ks++) {
        half8 a = *(const half8*)&H1a[(long)rowa * HIDDEN + ks * 32 + kq * 8];
        #pragma unroll
        for (int nt = 0; nt < 3; nt++) {
            half8 b = *(const half8*)&W2T[(nt * 16 + m16) * HIDDEN + ks * 32 + kq * 8];
            acc[nt] = __builtin_amdgcn_mfma_f32_16x16x32_f16(a, b, acc[nt], 0, 0, 0);
        }
    }
    const int gr0 = blockIdx.x * 64 + wave * 16 + kq * 4;
    float dd[4];
    #pragma unroll
    for (int r = 0; r < 4; r++) dd[r] = (gr0 + r < N_NODES) ? dinv[gr0 + r] : 0.f;
    #pragma unroll
    for (int nt = 0; nt < 3; nt++) {
        int c = nt * 16 + m16;
        if (c < NCLS) {
            #pragma unroll
            for (int r = 0; r < 4; r++) {
                if (gr0 + r < N_NODES)
                    H2s[(long)(gr0 + r) * NCLS + c] = __float2half_rn(dd[r] * acc[nt][r]);
            }
        }
    }
}

// ---------------- Aggregation 2 (+bias) -> fp32 out. 3 nodes x 20 half2-lanes per wave ----------------

__global__ __launch_bounds__(256) void k_agg2(const __half* __restrict__ H2s,
                                              const int* __restrict__ row_ptr,
                                              const int* __restrict__ col,
                                              const float* __restrict__ dinv,
                                              const float* __restrict__ b2,
                                              float* __restrict__ out) {
    const int wave = threadIdx.x >> 6;
    const int lane = threadIdx.x & 63;
    const int g = lane / 20;              // 0..2 active, 3 idle
    const int f = lane - g * 20;          // 0..19 -> feats 2f,2f+1
    const int d = blockIdx.x * 12 + wave * 3 + g;
    const bool act = (g < 3) && (d < N_NODES);
    int e0 = 0, e1 = 0;
    if (act) { e0 = row_ptr[d]; e1 = row_ptr[d + 1]; }
    const __half2* base2 = (const __half2*)H2s;   // row stride 20 half2
    float sx = 0.f, sy = 0.f;
    int e = e0;
    while (__any(e < e1)) {
        if (e < e1) {
            float2 v = __half22float2(base2[(long)col[e] * 20 + f]);
            sx += v.x; sy += v.y;
        }
        if (e + 1 < e1) {
            float2 v = __half22float2(base2[(long)col[e + 1] * 20 + f]);
            sx += v.x; sy += v.y;
        }
        e += 2;
    }
    if (act) {
        float2 v = __half22float2(base2[(long)d * 20 + f]);   // self-loop (pre-scaled)
        sx += v.x; sy += v.y;
        float dd = dinv[d];
        float2 bb = ((const float2*)b2)[f];
        ((float2*)out)[(long)d * 20 + f] = make_float2(dd * sx + bb.x, dd * sy + bb.y);
    }
}

// ---------------- launch ----------------

extern "C" void kernel_launch(void* const* d_in, const int* in_sizes, int n_in,
                              void* d_out, int out_size, void* d_ws, size_t ws_size,
                              hipStream_t stream) {
    const float* x  = (const float*)d_in[0];
    const int*   ei = (const int*)d_in[1];
    const float* W1 = (const float*)d_in[2];
    const float* b1 = (const float*)d_in[3];
    const float* W2 = (const float*)d_in[4];
    const float* b2 = (const float*)d_in[5];
    const int* srcE = ei;
    const int* dstE = ei + N_EDGES;

    int*   row_ptr = (int*)d_ws;                 // 100032
    int*   bfill   = row_ptr + 100032;           // 256
    int*   col     = bfill + 256;                // 1600000
    float* dinv    = (float*)(col + N_EDGES);    // 100032
    __half* H1s    = (__half*)(dinv + 100032);   // 12.8M halfs (25.6 MB)
    __half* H1a    = H1s + (long)N_NODES * HIDDEN;  // 12.8M halfs
    __half* H2s    = H1a + (long)N_NODES * HIDDEN;  // 4M halfs (8 MB)
    __half* W1T    = H2s + (long)N_NODES * NCLS;    // 32768 halfs
    __half* W2T    = W1T + IN_DIM * HIDDEN;         // 6144 halfs
    // bucket arrays alias H1s/H1a (dead before k_gemm1 writes H1s)
    int*   bsrc    = (int*)H1s;                  // 2.1M ints (8 MB)
    int*   bdst    = bsrc + N_BUCKETS * BCAP;    // 2.1M ints (8 MB)

    hipMemsetAsync(bfill, 0, N_BUCKETS * sizeof(int), stream);

    k_bin   <<<BIN_BLOCKS + 129, 256, 0, stream>>>(srcE, dstE, bfill, bsrc, bdst, W1, W1T, W2, W2T);
    k_build <<<N_BUCKETS, 256, 0, stream>>>(bfill, bsrc, bdst, row_ptr, dinv, col);

    k_gemm1 <<<(N_NODES + 127) / 128, 256, 0, stream>>>(x, W1T, dinv, H1s);
    k_agg1  <<<N_NODES / 4, 256, 0, stream>>>(H1s, row_ptr, col, dinv, b1, H1a);
    k_gemm2 <<<(N_NODES + 63) / 64, 256, 0, stream>>>(H1a, W2T, dinv, H2s);
    k_agg2  <<<(N_NODES + 11) / 12, 256, 0, stream>>>(H2s, row_ptr, col, dinv, b2, (float*)d_out);
}

// Round 8
// 375.103 us; speedup vs baseline: 1.2028x; 1.0779x over previous
//
#include <hip/hip_runtime.h>
#include <hip/hip_bf16.h>
#include <hip/hip_fp16.h>

#define N_NODES 100000
#define N_EDGES 1600000
#define IN_DIM 256
#define HIDDEN 128
#define NCLS 40
#define NCLS_PAD 48      // padded to 3 MFMA n-tiles

#define N_BUCKETS 256
#define NPB 391          // nodes per bucket = ceil(100000/256)
#define BCAP 8192        // bucket capacity (mean 6256, +24 sigma)
#define EPT 16           // edges per thread in k_bin
#define BIN_WG 4096      // edges per workgroup in k_bin (256*16)
#define BIN_BLOCKS 391   // ceil(N_EDGES / BIN_WG)

typedef __attribute__((ext_vector_type(8))) _Float16 half8;
typedef __attribute__((ext_vector_type(4))) _Float16 half4f;
typedef __attribute__((ext_vector_type(4))) float floatx4;

// ---------------- k_bin: LDS-staged edge bucketing (packed 8B records) + weight prep ----------------

__global__ __launch_bounds__(256) void k_bin(const int* __restrict__ src, const int* __restrict__ dst,
                                             int* __restrict__ bfill,
                                             unsigned long long* __restrict__ bpair,
                                             const float* __restrict__ W1, __half* __restrict__ W1T,
                                             const float* __restrict__ W2, __half* __restrict__ W2T) {
    const int t = threadIdx.x;
    if (blockIdx.x >= BIN_BLOCKS) {
        int wb = blockIdx.x - BIN_BLOCKS;
        if (wb < 128) {          // W1T: [n][k] fp16
            int i = wb * 256 + t;
            int k = i >> 7, n = i & 127;
            W1T[n * IN_DIM + k] = __float2half_rn(W1[i]);
        } else {                 // W2T: [n][k] fp16, 48 x 128, zero-pad n>=40
            for (int i = t; i < NCLS_PAD * HIDDEN; i += 256) {
                int n = i >> 7, k = i & 127;
                W2T[n * HIDDEN + k] = (n < NCLS) ? __float2half_rn(W2[k * NCLS + n]) : __float2half_rn(0.f);
            }
        }
        return;
    }
    __shared__ int hist[N_BUCKETS];
    __shared__ int bstart[N_BUCKETS];   // block-local exclusive scan of hist
    __shared__ int gbase[N_BUCKETS];    // global base for this block's chunk
    __shared__ unsigned long long stage[BIN_WG];   // 32 KB, bucket-ordered records
    __shared__ unsigned char bid[BIN_WG];          // 4 KB, bucket id per staged slot
    hist[t] = 0;
    __syncthreads();
    const long e0 = (long)blockIdx.x * BIN_WG;
    const int n_valid = (int)min((long)BIN_WG, (long)N_EDGES - e0);
    int msrc[EPT], mdst[EPT], moff[EPT];
    #pragma unroll
    for (int i = 0; i < EPT; i++) {
        long e = e0 + t + i * 256;
        if (e < N_EDGES) {
            msrc[i] = src[e];
            mdst[i] = dst[e];
            moff[i] = atomicAdd(&hist[mdst[i] / NPB], 1);
        } else {
            mdst[i] = -1;
        }
    }
    __syncthreads();
    if (t < 64) {   // wave 0: exclusive scan of hist[256] in 4 chunks
        int carry = 0;
        #pragma unroll
        for (int c = 0; c < 4; c++) {
            int idx = c * 64 + t;
            int hv = hist[idx];
            int s = hv;
            #pragma unroll
            for (int d2 = 1; d2 < 64; d2 <<= 1) {
                int u = __shfl_up(s, d2, 64);
                if (t >= d2) s += u;
            }
            bstart[idx] = carry + (s - hv);
            carry += __shfl(s, 63, 64);
        }
    }
    __syncthreads();
    int h = hist[t];
    gbase[t] = (h > 0) ? atomicAdd(&bfill[t], h) : 0;
    // stage records in bucket order
    #pragma unroll
    for (int i = 0; i < EPT; i++) {
        if (mdst[i] >= 0) {
            int b = mdst[i] / NPB;
            int pos = bstart[b] + moff[i];
            stage[pos] = ((unsigned long long)(unsigned)mdst[i] << 32) | (unsigned)msrc[i];
            bid[pos] = (unsigned char)b;
        }
    }
    __syncthreads();
    // linear copy-out: consecutive slots in same bucket -> consecutive global addresses
    for (int i = t; i < n_valid; i += 256) {
        int b = bid[i];
        int dest = gbase[b] + (i - bstart[b]);
        bpair[(long)b * BCAP + dest] = stage[i];
    }
}

// ---------------- k_build: histogram -> prefix -> row_ptr/dinv -> scatter ----------------

__global__ __launch_bounds__(256) void k_build(const int* __restrict__ bfill,
                                               const unsigned long long* __restrict__ bpair,
                                               int* __restrict__ row_ptr, float* __restrict__ dinv,
                                               int* __restrict__ col) {
    __shared__ int h[NPB];
    __shared__ int pfx[NPB];
    __shared__ int sred[4];
    const int b  = blockIdx.x;
    const int nb = b * NPB;
    const int nn = min(NPB, N_NODES - nb);
    const int t  = threadIdx.x;
    int v = (t < b) ? bfill[t] : 0;
    #pragma unroll
    for (int dl = 32; dl > 0; dl >>= 1) v += __shfl_down(v, dl, 64);
    if ((t & 63) == 0) sred[t >> 6] = v;
    for (int i = t; i < NPB; i += 256) h[i] = 0;
    __syncthreads();
    const int base_b = sred[0] + sred[1] + sred[2] + sred[3];
    const int n = bfill[b];
    for (int i = t; i < n; i += 256) {
        int dd = (int)(bpair[(long)b * BCAP + i] >> 32);
        atomicAdd(&h[dd - nb], 1);
    }
    __syncthreads();
    if (t < 64) {   // wave 0: exclusive scan of degrees
        int carry = 0;
        #pragma unroll
        for (int c = 0; c < (NPB + 63) / 64; c++) {
            int idx = c * 64 + t;
            int hv = (idx < nn) ? h[idx] : 0;
            int s = hv;
            #pragma unroll
            for (int d2 = 1; d2 < 64; d2 <<= 1) {
                int u = __shfl_up(s, d2, 64);
                if (t >= d2) s += u;
            }
            if (idx < nn) {
                int ex = base_b + carry + (s - hv);
                pfx[idx] = ex;
                row_ptr[nb + idx] = ex;
                dinv[nb + idx] = rsqrtf((float)(hv + 1));   // +1 self-loop
            }
            carry += __shfl(s, 63, 64);
        }
    }
    __syncthreads();
    for (int i = t; i < nn; i += 256) h[i] = 0;   // reuse as fill counters
    __syncthreads();
    for (int i = t; i < n; i += 256) {
        unsigned long long p = bpair[(long)b * BCAP + i];
        int dd = (int)(p >> 32);
        int ss = (int)(p & 0xFFFFFFFFu);
        int pos = pfx[dd - nb] + atomicAdd(&h[dd - nb], 1);
        col[pos] = ss;
    }
    if (b == 0 && t == 0) row_ptr[N_NODES] = N_EDGES;
}

// ---------------- GEMM1 (MFMA f16, 128x128 tile): H1s = dinv ⊙ (X @ W1) -> fp16 ----------------

__global__ __launch_bounds__(256) void k_gemm1(const float* __restrict__ X,
                                               const __half* __restrict__ W1T,
                                               const float* __restrict__ dinv,
                                               __half* __restrict__ H1s) {
    __shared__ __align__(16) _Float16 Asm[128][72];
    __shared__ __align__(16) _Float16 Bsm[128][72];
    const int tid  = threadIdx.x;
    const int wave = tid >> 6;
    const int lane = tid & 63;
    const int m16  = lane & 15;
    const int kq   = lane >> 4;
    const int row0 = blockIdx.x * 128;

    floatx4 acc[2][8];
    #pragma unroll
    for (int mt = 0; mt < 2; mt++)
        #pragma unroll
        for (int i = 0; i < 8; i++) acc[mt][i] = (floatx4)0.f;

    for (int kc = 0; kc < 4; kc++) {
        #pragma unroll
        for (int it = 0; it < 4; it++) {
            int u = tid + it * 256;
            int r = u >> 3, j = u & 7;
            int gr = row0 + r;
            float4 x0 = make_float4(0.f, 0.f, 0.f, 0.f), x1 = x0;
            if (gr < N_NODES) {
                const float* p = &X[(long)gr * IN_DIM + kc * 64 + j * 8];
                x0 = *(const float4*)p;
                x1 = *(const float4*)(p + 4);
            }
            half8 h;
            h[0] = (_Float16)x0.x; h[1] = (_Float16)x0.y; h[2] = (_Float16)x0.z; h[3] = (_Float16)x0.w;
            h[4] = (_Float16)x1.x; h[5] = (_Float16)x1.y; h[6] = (_Float16)x1.z; h[7] = (_Float16)x1.w;
            *(half8*)&Asm[r][j * 8] = h;
        }
        #pragma unroll
        for (int it = 0; it < 4; it++) {
            int u = tid + it * 256;
            int n = u >> 3, j = u & 7;
            float4 w = *(const float4*)&W1T[n * IN_DIM + kc * 64 + j * 8];
            *(float4*)&Bsm[n][j * 8] = w;
        }
        __syncthreads();
        #pragma unroll
        for (int ks = 0; ks < 2; ks++) {
            half8 a0 = *(const half8*)&Asm[wave * 32 + m16][ks * 32 + kq * 8];
            half8 a1 = *(const half8*)&Asm[wave * 32 + 16 + m16][ks * 32 + kq * 8];
            #pragma unroll
            for (int nt = 0; nt < 8; nt++) {
                half8 b = *(const half8*)&Bsm[nt * 16 + m16][ks * 32 + kq * 8];
                acc[0][nt] = __builtin_amdgcn_mfma_f32_16x16x32_f16(a0, b, acc[0][nt], 0, 0, 0);
                acc[1][nt] = __builtin_amdgcn_mfma_f32_16x16x32_f16(a1, b, acc[1][nt], 0, 0, 0);
            }
        }
        __syncthreads();
    }
    #pragma unroll
    for (int mt = 0; mt < 2; mt++) {
        const int gr0 = row0 + wave * 32 + mt * 16 + kq * 4;
        float dd[4];
        #pragma unroll
        for (int r = 0; r < 4; r++) dd[r] = (gr0 + r < N_NODES) ? dinv[gr0 + r] : 0.f;
        #pragma unroll
        for (int nt = 0; nt < 8; nt++) {
            int c = nt * 16 + m16;
            #pragma unroll
            for (int r = 0; r < 4; r++) {
                if (gr0 + r < N_NODES)
                    H1s[(long)(gr0 + r) * HIDDEN + c] = __float2half_rn(dd[r] * acc[mt][nt][r]);
            }
        }
    }
}

// ---------------- Aggregation 1 (+bias+ReLU) -> fp16 H1a. One wave/node ----------------

__global__ __launch_bounds__(256) void k_agg1(const __half* __restrict__ H1s,
                                              const int* __restrict__ row_ptr,
                                              const int* __restrict__ col,
                                              const float* __restrict__ dinv,
                                              const float* __restrict__ b1,
                                              __half* __restrict__ H1a) {
    int d = blockIdx.x * 4 + (threadIdx.x >> 6);
    int lane = threadIdx.x & 63;
    int e0 = row_ptr[d], e1 = row_ptr[d + 1];
    const __half2* base = (const __half2*)H1s;   // row stride 64 half2
    float ax = 0.f, ay = 0.f;
    int e = e0;
    for (; e + 3 < e1; e += 4) {
        int s0 = col[e], s1 = col[e + 1], s2 = col[e + 2], s3 = col[e + 3];
        float2 f0 = __half22float2(base[(long)s0 * 64 + lane]);
        float2 f1 = __half22float2(base[(long)s1 * 64 + lane]);
        float2 f2 = __half22float2(base[(long)s2 * 64 + lane]);
        float2 f3 = __half22float2(base[(long)s3 * 64 + lane]);
        ax += f0.x + f1.x + f2.x + f3.x;
        ay += f0.y + f1.y + f2.y + f3.y;
    }
    for (; e < e1; e++) {
        float2 f = __half22float2(base[(long)col[e] * 64 + lane]);
        ax += f.x; ay += f.y;
    }
    float2 fs = __half22float2(base[(long)d * 64 + lane]);   // self-loop (pre-scaled)
    ax += fs.x; ay += fs.y;
    float dd = dinv[d];
    float2 bb = ((const float2*)b1)[lane];
    float ox = fmaxf(dd * ax + bb.x, 0.f);
    float oy = fmaxf(dd * ay + bb.y, 0.f);
    ((__half2*)H1a)[(long)d * 64 + lane] = __halves2half2(__float2half_rn(ox), __float2half_rn(oy));
}

// ---------------- GEMM2 (MFMA f16, no LDS): H2s = dinv ⊙ (H1a @ W2) -> fp16 ----------------

__global__ __launch_bounds__(256) void k_gemm2(const __half* __restrict__ H1a,
                                               const __half* __restrict__ W2T,
                                               const float* __restrict__ dinv,
                                               __half* __restrict__ H2s) {
    const int wave = threadIdx.x >> 6;
    const int lane = threadIdx.x & 63;
    const int m16  = lane & 15;
    const int kq   = lane >> 4;
    const int rowa = min(blockIdx.x * 64 + wave * 16 + m16, N_NODES - 1);

    floatx4 acc[3];
    #pragma unroll
    for (int i = 0; i < 3; i++) acc[i] = (floatx4)0.f;

    #pragma unroll
    for (int ks = 0; ks < 4; ks++) {
        half8 a = *(const half8*)&H1a[(long)rowa * HIDDEN + ks * 32 + kq * 8];
        #pragma unroll
        for (int nt = 0; nt < 3; nt++) {
            half8 b = *(const half8*)&W2T[(nt * 16 + m16) * HIDDEN + ks * 32 + kq * 8];
            acc[nt] = __builtin_amdgcn_mfma_f32_16x16x32_f16(a, b, acc[nt], 0, 0, 0);
        }
    }
    const int gr0 = blockIdx.x * 64 + wave * 16 + kq * 4;
    float dd[4];
    #pragma unroll
    for (int r = 0; r < 4; r++) dd[r] = (gr0 + r < N_NODES) ? dinv[gr0 + r] : 0.f;
    #pragma unroll
    for (int nt = 0; nt < 3; nt++) {
        int c = nt * 16 + m16;
        if (c < NCLS) {
            #pragma unroll
            for (int r = 0; r < 4; r++) {
                if (gr0 + r < N_NODES)
                    H2s[(long)(gr0 + r) * NCLS + c] = __float2half_rn(dd[r] * acc[nt][r]);
            }
        }
    }
}

// ---------------- Aggregation 2 (+bias) -> fp32 out. 6 nodes x 10 half4-lanes per wave ----------------

__global__ __launch_bounds__(256) void k_agg2(const __half* __restrict__ H2s,
                                              const int* __restrict__ row_ptr,
                                              const int* __restrict__ col,
                                              const float* __restrict__ dinv,
                                              const float* __restrict__ b2,
                                              float* __restrict__ out) {
    const int wave = threadIdx.x >> 6;
    const int lane = threadIdx.x & 63;
    const int g = lane / 10;              // 0..5 active, g==6 (lanes 60-63) idle
    const int f = lane - g * 10;          // 0..9 -> feats 4f..4f+3
    const int d = blockIdx.x * 24 + wave * 6 + g;
    const bool act = (g < 6) && (d < N_NODES);
    int e0 = 0, e1 = 0;
    if (act) { e0 = row_ptr[d]; e1 = row_ptr[d + 1]; }
    const half4f* base4 = (const half4f*)H2s;   // row stride 10 half4
    float s0 = 0.f, s1 = 0.f, s2 = 0.f, s3 = 0.f;
    int e = e0;
    while (__any(e < e1)) {
        if (e < e1) {
            half4f v = base4[(long)col[e] * 10 + f];
            s0 += (float)v[0]; s1 += (float)v[1]; s2 += (float)v[2]; s3 += (float)v[3];
        }
        if (e + 1 < e1) {
            half4f v = base4[(long)col[e + 1] * 10 + f];
            s0 += (float)v[0]; s1 += (float)v[1]; s2 += (float)v[2]; s3 += (float)v[3];
        }
        e += 2;
    }
    if (act) {
        half4f v = base4[(long)d * 10 + f];   // self-loop (pre-scaled)
        s0 += (float)v[0]; s1 += (float)v[1]; s2 += (float)v[2]; s3 += (float)v[3];
        float dd = dinv[d];
        float4 bb = ((const float4*)b2)[f];
        float4 o = make_float4(dd * s0 + bb.x, dd * s1 + bb.y, dd * s2 + bb.z, dd * s3 + bb.w);
        ((float4*)out)[(long)d * 10 + f] = o;
    }
}

// ---------------- launch ----------------

extern "C" void kernel_launch(void* const* d_in, const int* in_sizes, int n_in,
                              void* d_out, int out_size, void* d_ws, size_t ws_size,
                              hipStream_t stream) {
    const float* x  = (const float*)d_in[0];
    const int*   ei = (const int*)d_in[1];
    const float* W1 = (const float*)d_in[2];
    const float* b1 = (const float*)d_in[3];
    const float* W2 = (const float*)d_in[4];
    const float* b2 = (const float*)d_in[5];
    const int* srcE = ei;
    const int* dstE = ei + N_EDGES;

    int*   row_ptr = (int*)d_ws;                 // 100032
    int*   bfill   = row_ptr + 100032;           // 256
    int*   col     = bfill + 256;                // 1600000
    float* dinv    = (float*)(col + N_EDGES);    // 100032 (+pad to 16B)
    __half* H1s    = (__half*)(dinv + 100032);   // 12.8M halfs (25.6 MB)
    __half* H1a    = H1s + (long)N_NODES * HIDDEN;  // 12.8M halfs
    __half* H2s    = H1a + (long)N_NODES * HIDDEN;  // 4M halfs (8 MB)
    __half* W1T    = H2s + (long)N_NODES * NCLS;    // 32768 halfs
    __half* W2T    = W1T + IN_DIM * HIDDEN;         // 6144 halfs
    // packed bucket array aliases H1s/H1a (dead before k_gemm1 writes H1s); 8B-aligned
    unsigned long long* bpair = (unsigned long long*)H1s;   // 2.1M entries (16.8 MB)

    hipMemsetAsync(bfill, 0, N_BUCKETS * sizeof(int), stream);

    k_bin   <<<BIN_BLOCKS + 129, 256, 0, stream>>>(srcE, dstE, bfill, bpair, W1, W1T, W2, W2T);
    k_build <<<N_BUCKETS, 256, 0, stream>>>(bfill, bpair, row_ptr, dinv, col);

    k_gemm1 <<<(N_NODES + 127) / 128, 256, 0, stream>>>(x, W1T, dinv, H1s);
    k_agg1  <<<N_NODES / 4, 256, 0, stream>>>(H1s, row_ptr, col, dinv, b1, H1a);
    k_gemm2 <<<(N_NODES + 63) / 64, 256, 0, stream>>>(H1a, W2T, dinv, H2s);
    k_agg2  <<<(N_NODES + 23) / 24, 256, 0, stream>>>(H2s, row_ptr, col, dinv, b2, (float*)d_out);
}

// Round 9
// 358.764 us; speedup vs baseline: 1.2575x; 1.0455x over previous
//
#include <hip/hip_runtime.h>
#include <hip/hip_bf16.h>
#include <hip/hip_fp16.h>

#define N_NODES 100000
#define N_EDGES 1600000
#define IN_DIM 256
#define HIDDEN 128
#define NCLS 40
#define NCLS_PAD 48      // padded to 3 MFMA n-tiles

#define N_BUCKETS 256
#define NPB 391          // nodes per bucket = ceil(100000/256)
#define BCAP 8192        // bucket capacity (mean 6256, +24 sigma)
#define EPT 16           // edges per thread in bin phase
#define BIN_WG 4096      // edges per workgroup (256*16)
#define BIN_BLOCKS 391   // ceil(N_EDGES / BIN_WG)
#define GEMM1_BLOCKS 782 // ceil(N_NODES / 128)

typedef __attribute__((ext_vector_type(8))) _Float16 half8;
typedef __attribute__((ext_vector_type(4))) _Float16 half4f;
typedef __attribute__((ext_vector_type(4))) float floatx4;

// ---------------- k_prep: W1T / W2T fp16 transposes + bfill zero ----------------

__global__ __launch_bounds__(256) void k_prep(const float* __restrict__ W1, __half* __restrict__ W1T,
                                              const float* __restrict__ W2, __half* __restrict__ W2T,
                                              int* __restrict__ bfill) {
    const int t = threadIdx.x;
    if (blockIdx.x < 128) {              // W1T: [n][k] fp16, 128 x 256
        int i = blockIdx.x * 256 + t;
        int k = i >> 7, n = i & 127;
        W1T[n * IN_DIM + k] = __float2half_rn(W1[i]);
    } else if (blockIdx.x == 128) {      // W2T: [n][k] fp16, 48 x 128, zero-pad n>=40
        for (int i = t; i < NCLS_PAD * HIDDEN; i += 256) {
            int n = i >> 7, k = i & 127;
            W2T[n * HIDDEN + k] = (n < NCLS) ? __float2half_rn(W2[k * NCLS + n]) : __float2half_rn(0.f);
        }
    } else {
        bfill[t] = 0;
    }
}

// ---------------- k_binmm: [0,391) LDS-staged edge binning  ∥  [391,1173) GEMM1 (unscaled) ----------------

__global__ __launch_bounds__(256) void k_binmm(const int* __restrict__ src, const int* __restrict__ dst,
                                               int* __restrict__ bfill,
                                               unsigned long long* __restrict__ bpair,
                                               const float* __restrict__ X,
                                               const __half* __restrict__ W1T,
                                               __half* __restrict__ H1s) {
    __shared__ __align__(16) char smraw[39936];   // union: bin(39936) / gemm1(36864)
    const int t = threadIdx.x;

    if (blockIdx.x < BIN_BLOCKS) {
        // ---- bin phase ----
        int* hist   = (int*)smraw;                               // 256
        int* bstart = hist + 256;                                // 256
        int* gbase  = bstart + 256;                              // 256
        unsigned long long* stage = (unsigned long long*)(smraw + 3072);   // 4096 (32 KB)
        unsigned char* bid = (unsigned char*)(smraw + 3072 + 32768);       // 4096
        hist[t] = 0;
        __syncthreads();
        const long e0 = (long)blockIdx.x * BIN_WG;
        const int n_valid = (int)min((long)BIN_WG, (long)N_EDGES - e0);
        int msrc[EPT], mdst[EPT], moff[EPT];
        #pragma unroll
        for (int i = 0; i < EPT; i++) {
            long e = e0 + t + i * 256;
            if (e < N_EDGES) {
                msrc[i] = src[e];
                mdst[i] = dst[e];
                moff[i] = atomicAdd(&hist[mdst[i] / NPB], 1);
            } else {
                mdst[i] = -1;
            }
        }
        __syncthreads();
        if (t < 64) {   // wave 0: exclusive scan of hist[256]
            int carry = 0;
            #pragma unroll
            for (int c = 0; c < 4; c++) {
                int idx = c * 64 + t;
                int hv = hist[idx];
                int s = hv;
                #pragma unroll
                for (int d2 = 1; d2 < 64; d2 <<= 1) {
                    int u = __shfl_up(s, d2, 64);
                    if (t >= d2) s += u;
                }
                bstart[idx] = carry + (s - hv);
                carry += __shfl(s, 63, 64);
            }
        }
        __syncthreads();
        int h = hist[t];
        gbase[t] = (h > 0) ? atomicAdd(&bfill[t], h) : 0;
        #pragma unroll
        for (int i = 0; i < EPT; i++) {
            if (mdst[i] >= 0) {
                int b = mdst[i] / NPB;
                int pos = bstart[b] + moff[i];
                stage[pos] = ((unsigned long long)(unsigned)mdst[i] << 32) | (unsigned)msrc[i];
                bid[pos] = (unsigned char)b;
            }
        }
        __syncthreads();
        for (int i = t; i < n_valid; i += 256) {
            int b = bid[i];
            int dest = gbase[b] + (i - bstart[b]);
            bpair[(long)b * BCAP + dest] = stage[i];
        }
        return;
    }

    // ---- gemm1 phase (128x128 tile, MFMA f16, NO dinv scaling) ----
    _Float16 (*Asm)[72] = (_Float16(*)[72])smraw;
    _Float16 (*Bsm)[72] = (_Float16(*)[72])(smraw + 128 * 72 * 2);
    const int wave = t >> 6;
    const int lane = t & 63;
    const int m16  = lane & 15;
    const int kq   = lane >> 4;
    const int row0 = (blockIdx.x - BIN_BLOCKS) * 128;

    floatx4 acc[2][8];
    #pragma unroll
    for (int mt = 0; mt < 2; mt++)
        #pragma unroll
        for (int i = 0; i < 8; i++) acc[mt][i] = (floatx4)0.f;

    for (int kc = 0; kc < 4; kc++) {
        #pragma unroll
        for (int it = 0; it < 4; it++) {
            int u = t + it * 256;
            int r = u >> 3, j = u & 7;
            int gr = row0 + r;
            float4 x0 = make_float4(0.f, 0.f, 0.f, 0.f), x1 = x0;
            if (gr < N_NODES) {
                const float* p = &X[(long)gr * IN_DIM + kc * 64 + j * 8];
                x0 = *(const float4*)p;
                x1 = *(const float4*)(p + 4);
            }
            half8 hh;
            hh[0] = (_Float16)x0.x; hh[1] = (_Float16)x0.y; hh[2] = (_Float16)x0.z; hh[3] = (_Float16)x0.w;
            hh[4] = (_Float16)x1.x; hh[5] = (_Float16)x1.y; hh[6] = (_Float16)x1.z; hh[7] = (_Float16)x1.w;
            *(half8*)&Asm[r][j * 8] = hh;
        }
        #pragma unroll
        for (int it = 0; it < 4; it++) {
            int u = t + it * 256;
            int n = u >> 3, j = u & 7;
            float4 w = *(const float4*)&W1T[n * IN_DIM + kc * 64 + j * 8];
            *(float4*)&Bsm[n][j * 8] = w;
        }
        __syncthreads();
        #pragma unroll
        for (int ks = 0; ks < 2; ks++) {
            half8 a0 = *(const half8*)&Asm[wave * 32 + m16][ks * 32 + kq * 8];
            half8 a1 = *(const half8*)&Asm[wave * 32 + 16 + m16][ks * 32 + kq * 8];
            #pragma unroll
            for (int nt = 0; nt < 8; nt++) {
                half8 b = *(const half8*)&Bsm[nt * 16 + m16][ks * 32 + kq * 8];
                acc[0][nt] = __builtin_amdgcn_mfma_f32_16x16x32_f16(a0, b, acc[0][nt], 0, 0, 0);
                acc[1][nt] = __builtin_amdgcn_mfma_f32_16x16x32_f16(a1, b, acc[1][nt], 0, 0, 0);
            }
        }
        __syncthreads();
    }
    #pragma unroll
    for (int mt = 0; mt < 2; mt++) {
        const int gr0 = row0 + wave * 32 + mt * 16 + kq * 4;
        #pragma unroll
        for (int nt = 0; nt < 8; nt++) {
            int c = nt * 16 + m16;
            #pragma unroll
            for (int r = 0; r < 4; r++) {
                if (gr0 + r < N_NODES)
                    H1s[(long)(gr0 + r) * HIDDEN + c] = __float2half_rn(acc[mt][nt][r]);
            }
        }
    }
}

// ---------------- k_build: histogram -> prefix -> row_ptr/dinv -> scatter -> H1 row-scale ----------------

__global__ __launch_bounds__(256) void k_build(const int* __restrict__ bfill,
                                               const unsigned long long* __restrict__ bpair,
                                               int* __restrict__ row_ptr, float* __restrict__ dinv,
                                               int* __restrict__ col, __half* __restrict__ H1s) {
    __shared__ int h[NPB];
    __shared__ int pfx[NPB];
    __shared__ float sdinv[NPB];
    __shared__ int sred[4];
    const int b  = blockIdx.x;
    const int nb = b * NPB;
    const int nn = min(NPB, N_NODES - nb);
    const int t  = threadIdx.x;
    int v = (t < b) ? bfill[t] : 0;
    #pragma unroll
    for (int dl = 32; dl > 0; dl >>= 1) v += __shfl_down(v, dl, 64);
    if ((t & 63) == 0) sred[t >> 6] = v;
    for (int i = t; i < NPB; i += 256) h[i] = 0;
    __syncthreads();
    const int base_b = sred[0] + sred[1] + sred[2] + sred[3];
    const int n = bfill[b];
    for (int i = t; i < n; i += 256) {
        int dd = (int)(bpair[(long)b * BCAP + i] >> 32);
        atomicAdd(&h[dd - nb], 1);
    }
    __syncthreads();
    if (t < 64) {   // wave 0: exclusive scan of degrees
        int carry = 0;
        #pragma unroll
        for (int c = 0; c < (NPB + 63) / 64; c++) {
            int idx = c * 64 + t;
            int hv = (idx < nn) ? h[idx] : 0;
            int s = hv;
            #pragma unroll
            for (int d2 = 1; d2 < 64; d2 <<= 1) {
                int u = __shfl_up(s, d2, 64);
                if (t >= d2) s += u;
            }
            if (idx < nn) {
                int ex = base_b + carry + (s - hv);
                pfx[idx] = ex;
                row_ptr[nb + idx] = ex;
                float dv = rsqrtf((float)(hv + 1));   // +1 self-loop
                dinv[nb + idx] = dv;
                sdinv[idx] = dv;
            }
            carry += __shfl(s, 63, 64);
        }
    }
    __syncthreads();
    for (int i = t; i < nn; i += 256) h[i] = 0;   // reuse as fill counters
    __syncthreads();
    for (int i = t; i < n; i += 256) {
        unsigned long long p = bpair[(long)b * BCAP + i];
        int dd = (int)(p >> 32);
        int ss = (int)(p & 0xFFFFFFFFu);
        int pos = pfx[dd - nb] + atomicAdd(&h[dd - nb], 1);
        col[pos] = ss;
    }
    // scale this bucket's H1 rows by dinv (coalesced; fills otherwise-idle CUs)
    __half2* Hp = (__half2*)H1s;
    for (int i = t; i < nn * 64; i += 256) {
        int r = i >> 6, o = i & 63;
        float dv = sdinv[r];
        float2 f = __half22float2(Hp[(long)(nb + r) * 64 + o]);
        Hp[(long)(nb + r) * 64 + o] = __halves2half2(__float2half_rn(f.x * dv), __float2half_rn(f.y * dv));
    }
    if (b == 0 && t == 0) row_ptr[N_NODES] = N_EDGES;
}

// ---------------- k_agg1g2: Agg1 (+bias+ReLU, pre-scale) + MFMA GEMM2 -> H2s fp16 ----------------
// Block = 16 nodes. Each wave aggregates 4 nodes (half2/lane) into pre-scaled fp16 LDS
// rows; then waves 0-2 each compute one 16-col MFMA n-tile of H2s[16 nodes].

__global__ __launch_bounds__(256) void k_agg1g2(const __half* __restrict__ H1s,
                                                const int* __restrict__ row_ptr,
                                                const int* __restrict__ col,
                                                const float* __restrict__ dinv,
                                                const float* __restrict__ b1,
                                                const __half* __restrict__ W2T,
                                                __half* __restrict__ H2s) {
    __shared__ __align__(16) _Float16 rows[16][136];   // +8 pad: 16B-aligned, 2-way-max banks
    const int wave = threadIdx.x >> 6;
    const int lane = threadIdx.x & 63;
    const __half2* base = (const __half2*)H1s;   // row stride 64 half2
    const float2 bb = ((const float2*)b1)[lane];
    const int d00 = blockIdx.x * 16 + wave * 4;

    #pragma unroll
    for (int i = 0; i < 4; i++) {
        const int d = d00 + i;
        int e0 = row_ptr[d], e1 = row_ptr[d + 1];
        float ax = 0.f, ay = 0.f;
        int e = e0;
        for (; e + 3 < e1; e += 4) {
            int s0 = col[e], s1 = col[e + 1], s2 = col[e + 2], s3 = col[e + 3];
            float2 f0 = __half22float2(base[(long)s0 * 64 + lane]);
            float2 f1 = __half22float2(base[(long)s1 * 64 + lane]);
            float2 f2 = __half22float2(base[(long)s2 * 64 + lane]);
            float2 f3 = __half22float2(base[(long)s3 * 64 + lane]);
            ax += f0.x + f1.x + f2.x + f3.x;
            ay += f0.y + f1.y + f2.y + f3.y;
        }
        for (; e < e1; e++) {
            float2 f = __half22float2(base[(long)col[e] * 64 + lane]);
            ax += f.x; ay += f.y;
        }
        float2 fs = __half22float2(base[(long)d * 64 + lane]);   // self-loop (pre-scaled)
        ax += fs.x; ay += fs.y;
        const float dd = dinv[d];
        // pre-scale the relu row by dd so the MFMA needs no post-scale
        float ox = fmaxf(dd * ax + bb.x, 0.f) * dd;
        float oy = fmaxf(dd * ay + bb.y, 0.f) * dd;
        *(__half2*)&rows[wave * 4 + i][lane * 2] =
            __halves2half2(__float2half_rn(ox), __float2half_rn(oy));
    }
    __syncthreads();

    if (wave < 3) {   // 3 n-tiles of 16 cols (48 padded, 40 real)
        const int m16 = lane & 15;
        const int kq  = lane >> 4;
        floatx4 acc = (floatx4)0.f;
        #pragma unroll
        for (int ks = 0; ks < 4; ks++) {
            half8 a = *(const half8*)&rows[m16][ks * 32 + kq * 8];
            half8 b = *(const half8*)&W2T[(wave * 16 + m16) * HIDDEN + ks * 32 + kq * 8];
            acc = __builtin_amdgcn_mfma_f32_16x16x32_f16(a, b, acc, 0, 0, 0);
        }
        const int c = wave * 16 + m16;
        if (c < NCLS) {
            const int gr0 = blockIdx.x * 16 + kq * 4;
            #pragma unroll
            for (int r = 0; r < 4; r++)
                H2s[(long)(gr0 + r) * NCLS + c] = __float2half_rn(acc[r]);
        }
    }
}

// ---------------- Aggregation 2 (+bias) -> fp32 out. 6 nodes x 10 half4-lanes per wave ----------------

__global__ __launch_bounds__(256) void k_agg2(const __half* __restrict__ H2s,
                                              const int* __restrict__ row_ptr,
                                              const int* __restrict__ col,
                                              const float* __restrict__ dinv,
                                              const float* __restrict__ b2,
                                              float* __restrict__ out) {
    const int wave = threadIdx.x >> 6;
    const int lane = threadIdx.x & 63;
    const int g = lane / 10;              // 0..5 active, lanes 60-63 idle
    const int f = lane - g * 10;          // 0..9 -> feats 4f..4f+3
    const int d = blockIdx.x * 24 + wave * 6 + g;
    const bool act = (g < 6) && (d < N_NODES);
    int e0 = 0, e1 = 0;
    if (act) { e0 = row_ptr[d]; e1 = row_ptr[d + 1]; }
    const half4f* base4 = (const half4f*)H2s;   // row stride 10 half4
    float s0 = 0.f, s1 = 0.f, s2 = 0.f, s3 = 0.f;
    int e = e0;
    while (__any(e < e1)) {
        if (e < e1) {
            half4f v = base4[(long)col[e] * 10 + f];
            s0 += (float)v[0]; s1 += (float)v[1]; s2 += (float)v[2]; s3 += (float)v[3];
        }
        if (e + 1 < e1) {
            half4f v = base4[(long)col[e + 1] * 10 + f];
            s0 += (float)v[0]; s1 += (float)v[1]; s2 += (float)v[2]; s3 += (float)v[3];
        }
        e += 2;
    }
    if (act) {
        half4f v = base4[(long)d * 10 + f];   // self-loop (pre-scaled)
        s0 += (float)v[0]; s1 += (float)v[1]; s2 += (float)v[2]; s3 += (float)v[3];
        float dd = dinv[d];
        float4 bbv = ((const float4*)b2)[f];
        float4 o = make_float4(dd * s0 + bbv.x, dd * s1 + bbv.y, dd * s2 + bbv.z, dd * s3 + bbv.w);
        ((float4*)out)[(long)d * 10 + f] = o;
    }
}

// ---------------- launch ----------------

extern "C" void kernel_launch(void* const* d_in, const int* in_sizes, int n_in,
                              void* d_out, int out_size, void* d_ws, size_t ws_size,
                              hipStream_t stream) {
    const float* x  = (const float*)d_in[0];
    const int*   ei = (const int*)d_in[1];
    const float* W1 = (const float*)d_in[2];
    const float* b1 = (const float*)d_in[3];
    const float* W2 = (const float*)d_in[4];
    const float* b2 = (const float*)d_in[5];
    const int* srcE = ei;
    const int* dstE = ei + N_EDGES;

    int*   row_ptr = (int*)d_ws;                    // 100032 ints
    int*   bfill   = row_ptr + 100032;              // 256
    int*   col     = bfill + 256;                   // 1600000
    float* dinv    = (float*)(col + N_EDGES);       // 100032 floats
    __half* H1s    = (__half*)(dinv + 100032);      // 12.8M halfs (25.6 MB)
    __half* H2s    = H1s + (long)N_NODES * HIDDEN;  // 4M halfs (8 MB)
    __half* W1T    = H2s + (long)N_NODES * NCLS;    // 32768 halfs
    __half* W2T    = W1T + IN_DIM * HIDDEN;         // 6144 halfs
    unsigned long long* bpair = (unsigned long long*)(W2T + NCLS_PAD * HIDDEN);  // 2.1M (16.8 MB)

    k_prep   <<<130, 256, 0, stream>>>(W1, W1T, W2, W2T, bfill);
    k_binmm  <<<BIN_BLOCKS + GEMM1_BLOCKS, 256, 0, stream>>>(srcE, dstE, bfill, bpair, x, W1T, H1s);
    k_build  <<<N_BUCKETS, 256, 0, stream>>>(bfill, bpair, row_ptr, dinv, col, H1s);
    k_agg1g2 <<<N_NODES / 16, 256, 0, stream>>>(H1s, row_ptr, col, dinv, b1, W2T, H2s);
    k_agg2   <<<(N_NODES + 23) / 24, 256, 0, stream>>>(H2s, row_ptr, col, dinv, b2, (float*)d_out);
}